// Round 13
// baseline (61.180 us; speedup 1.0000x reference)
//
#include <hip/hip_runtime.h>
#include <hip/hip_bf16.h>
#include <hip/hip_fp16.h>

// ---------------- constants (problem is fixed-shape) ----------------
#define SEQ   2048
#define DIM   1024
#define NHEAD 16
#define HD    64
// grid (8,16,16), window (3,5,5) -> half windows 1,2,2
#define QSCALE 0.18033688011112042f   // (1/sqrt(64)) * log2(e), folded into Q

typedef _Float16 half8 __attribute__((ext_vector_type(8)));
typedef _Float16 half4 __attribute__((ext_vector_type(4)));
typedef float    floatx4 __attribute__((ext_vector_type(4)));

// async global->LDS, 16B per lane; LDS dest is wave-uniform base + lane*16
__device__ __forceinline__ void gload16(const void* g, void* l) {
    __builtin_amdgcn_global_load_lds(
        (const __attribute__((address_space(1))) unsigned int*)g,
        (__attribute__((address_space(3))) unsigned int*)l, 16, 0, 0);
}

#define VMCNT(n) asm volatile("s_waitcnt vmcnt(" #n ")" ::: "memory")
#define LGKM0()  asm volatile("s_waitcnt lgkmcnt(0)" ::: "memory")
#define BAR()    __builtin_amdgcn_s_barrier()

// ---------------- 1+2 merged prep (vectorized) ----------------
// z<4: 64x64 transpose-cvt tiles through padded LDS (float4 loads, half8 stores)
// z=4: H f32->f16, float4 x2 -> half8, 32 elems/thread
__global__ __launch_bounds__(256) void prep(
        const float* __restrict__ H, _Float16* __restrict__ Hf,
        const float* __restrict__ W0, const float* __restrict__ W1,
        const float* __restrict__ W2, const float* __restrict__ W3,
        _Float16* __restrict__ T) {
    __shared__ float tile[64][65];    // +1 pad: both phases <=2-way bank aliasing
    int z = blockIdx.z;
    int t = threadIdx.x;
    if (z < 4) {
        const float* W = (z == 0) ? W0 : (z == 1) ? W1 : (z == 2) ? W2 : W3;
        _Float16* Tz = T + (size_t)z * (DIM * DIM);
        int bx = blockIdx.x * 64;     // n base
        int by = blockIdx.y * 64;     // k base
        #pragma unroll
        for (int i = 0; i < 4; i++) {
            int id = t + i * 256;
            int r = id >> 4;                  // k_local 0..63
            int c = (id & 15) * 4;            // n_local 0..60
            float4 v = *reinterpret_cast<const float4*>(W + (size_t)(by + r) * DIM + bx + c);
            tile[r][c] = v.x; tile[r][c + 1] = v.y; tile[r][c + 2] = v.z; tile[r][c + 3] = v.w;
        }
        __syncthreads();
        #pragma unroll
        for (int i = 0; i < 2; i++) {
            int id = t + i * 256;
            int nr = id >> 3;                 // n_local 0..63
            int c8 = id & 7;                  // k chunk
            half8 o;
            #pragma unroll
            for (int j = 0; j < 8; j++) o[j] = (_Float16)tile[c8 * 8 + j][nr];
            *reinterpret_cast<half8*>(Tz + (size_t)(bx + nr) * DIM + by + c8 * 8) = o;
        }
    } else {
        int wg = blockIdx.y * 16 + blockIdx.x;   // 0..255
        #pragma unroll
        for (int i = 0; i < 4; i++) {
            int base = ((wg * 4 + i) * 256 + t) * 8;
            float4 v0 = *reinterpret_cast<const float4*>(H + base);
            float4 v1 = *reinterpret_cast<const float4*>(H + base + 4);
            half8 o = { (_Float16)v0.x, (_Float16)v0.y, (_Float16)v0.z, (_Float16)v0.w,
                        (_Float16)v1.x, (_Float16)v1.y, (_Float16)v1.z, (_Float16)v1.w };
            *reinterpret_cast<half8*>(Hf + base) = o;
        }
    }
}

// ---------------- GEMM core: 128x64 tile, BK=64, 2-deep counted-vmcnt pipeline ----
// (round-11 proven; used by V^T path and gemm_o)
// LDS/buffer: A 16KB + B 8KB = 24KB; 2 buffers = 48KB. vmcnt(6); never 0 in loop.
__device__ __forceinline__ void gemm_core64(const _Float16* __restrict__ Ap,
                                            const _Float16* __restrict__ Bp,
                                            char* lds, floatx4 (&acc)[4][2]) {
    const int tid  = threadIdx.x;
    const int lane = tid & 63;
    const int wid  = tid >> 6;
    const int wr = wid >> 1, wc = wid & 1;
    const int r16 = lane & 15;
    const int kk  = (lane >> 4) * 8;

    const int srow = tid >> 2, scol = (tid & 3) * 8;
    const _Float16* As0 = Ap + (size_t)srow * DIM + scol;   // rows 0..63 (+64 via i&1)
    const _Float16* Bs0 = Bp + (size_t)srow * DIM + scol;   // rows 0..63

    auto stage = [&](int buf, int t) {
        char* Ad = lds + buf * 24576;
        char* Bd = Ad + 16384;
        int k0 = t * 64;
        #pragma unroll
        for (int i = 0; i < 4; i++) {        // A: two row-halves x two ks-halves
            int off = (i & 1) * 64 * DIM + (i >> 1) * 32 + k0;
            gload16(As0 + off, Ad + i * 4096 + wid * 1024);
        }
        #pragma unroll
        for (int j = 0; j < 2; j++)          // B: 64 rows, ks-half j
            gload16(Bs0 + j * 32 + k0, Bd + j * 4096 + wid * 1024);
    };

    auto compute = [&](int buf) {
        char* Ad = lds + buf * 24576;
        char* Bd = Ad + 16384;
        #pragma unroll
        for (int ks = 0; ks < 2; ks++) {
            half8 a[4], b[2];
            #pragma unroll
            for (int m = 0; m < 4; m++)
                a[m] = *reinterpret_cast<half8*>(Ad + ks * 8192 + (wr * 64 + m * 16 + r16) * 64 + kk * 2);
            #pragma unroll
            for (int n = 0; n < 2; n++)
                b[n] = *reinterpret_cast<half8*>(Bd + ks * 4096 + (wc * 32 + n * 16 + r16) * 64 + kk * 2);
            #pragma unroll
            for (int m = 0; m < 4; m++)
                #pragma unroll
                for (int n = 0; n < 2; n++)
                    acc[m][n] = __builtin_amdgcn_mfma_f32_16x16x32_f16(a[m], b[n], acc[m][n], 0, 0, 0);
        }
    };

    stage(0, 0);
    stage(1, 1);                               // 12 loads/wave outstanding
    #pragma unroll 1
    for (int t = 0; t < 14; t += 2) {
        VMCNT(6); BAR();
        compute(0);
        BAR();
        stage(0, t + 2);
        VMCNT(6); BAR();
        compute(1);
        BAR();
        stage(1, t + 3);
    }
    VMCNT(6); BAR();
    compute(0);
    BAR();
    VMCNT(0); BAR();
    compute(1);
}

// ---------------- 3. QKV projections: fused Q+K (shared A-tile) + V^T ------------
// z=0: FUSED Q,K = H*(Wq^T,Wk^T): one A(H)-stage feeds TWO B-panels -> 33% fewer
//      staged bytes, 32 MFMA per barrier-pair. LDS: A 16KB + Bq 8KB + Bk 8KB = 32KB
//      per buffer, x2 = 64KB. 8 loads/wave/step -> vmcnt(8), never 0 in loop.
// z=1: V^T = Wv^T * H^T (row-major [1024][2048]) on the plain core.
__global__ __launch_bounds__(256) void gemm_qkv(
        const _Float16* __restrict__ Hf, const _Float16* __restrict__ Wt,
        _Float16* __restrict__ Qp, _Float16* __restrict__ Kp, _Float16* __restrict__ Vt) {
    __shared__ char lds[65536];

    // XCD-aware chunked remap of 512 workgroups (512 % 8 == 0 -> bijective)
    int lin = blockIdx.x + 256 * blockIdx.z;     // 0..511
    int swz = (lin & 7) * 64 + (lin >> 3);
    int z   = swz >> 8;            // 0: fused QK, 1: V^T
    int rem = swz & 255;

    const int tid  = threadIdx.x;
    const int lane = tid & 63;
    const int wid  = tid >> 6;
    const int wr = wid >> 1, wc = wid & 1;
    const int r16 = lane & 15;
    const int kk  = (lane >> 4) * 8;
    const int srow = tid >> 2, scol = (tid & 3) * 8;

    if (z == 0) {
        int tm = rem & 15, tn = rem >> 4;            // 16 m x 16 n(=head)
        const _Float16* As0 = Hf + (size_t)tm * 128 * DIM + (size_t)srow * DIM + scol;
        const _Float16* Bq0 = Wt + (size_t)tn * 64 * DIM + (size_t)srow * DIM + scol;
        const _Float16* Bk0 = Wt + (size_t)DIM * DIM + (size_t)tn * 64 * DIM + (size_t)srow * DIM + scol;
        floatx4 accQ[4][2] = {}, accK[4][2] = {};

        auto stage = [&](int buf, int t) {
            char* Ad = lds + buf * 32768;
            int k0 = t * 64;
            #pragma unroll
            for (int i = 0; i < 4; i++) {
                int off = (i & 1) * 64 * DIM + (i >> 1) * 32 + k0;
                gload16(As0 + off, Ad + i * 4096 + wid * 1024);
            }
            #pragma unroll
            for (int j = 0; j < 2; j++) {
                gload16(Bq0 + j * 32 + k0, Ad + 16384 + j * 4096 + wid * 1024);
                gload16(Bk0 + j * 32 + k0, Ad + 24576 + j * 4096 + wid * 1024);
            }
        };
        auto compute = [&](int buf) {
            char* Ad = lds + buf * 32768;
            #pragma unroll
            for (int ks = 0; ks < 2; ks++) {
                half8 a[4], bq[2], bk[2];
                #pragma unroll
                for (int m = 0; m < 4; m++)
                    a[m] = *reinterpret_cast<half8*>(Ad + ks * 8192 + (wr * 64 + m * 16 + r16) * 64 + kk * 2);
                #pragma unroll
                for (int n = 0; n < 2; n++) {
                    bq[n] = *reinterpret_cast<half8*>(Ad + 16384 + ks * 4096 + (wc * 32 + n * 16 + r16) * 64 + kk * 2);
                    bk[n] = *reinterpret_cast<half8*>(Ad + 24576 + ks * 4096 + (wc * 32 + n * 16 + r16) * 64 + kk * 2);
                }
                #pragma unroll
                for (int m = 0; m < 4; m++)
                    #pragma unroll
                    for (int n = 0; n < 2; n++) {
                        accQ[m][n] = __builtin_amdgcn_mfma_f32_16x16x32_f16(a[m], bq[n], accQ[m][n], 0, 0, 0);
                        accK[m][n] = __builtin_amdgcn_mfma_f32_16x16x32_f16(a[m], bk[n], accK[m][n], 0, 0, 0);
                    }
            }
        };

        stage(0, 0);
        stage(1, 1);                           // 16 loads/wave outstanding
        #pragma unroll 1
        for (int t = 0; t < 14; t += 2) {
            VMCNT(8); BAR();                   // older buffer's 8 loads complete
            compute(0);
            BAR();
            stage(0, t + 2);
            VMCNT(8); BAR();
            compute(1);
            BAR();
            stage(1, t + 3);
        }
        VMCNT(8); BAR();
        compute(0);
        BAR();
        VMCNT(0); BAR();
        compute(1);

        // epilogue: head == tn; Q scaled by QSCALE
        #pragma unroll
        for (int m = 0; m < 4; m++) {
            #pragma unroll
            for (int n = 0; n < 2; n++) {
                #pragma unroll
                for (int r = 0; r < 4; r++) {
                    int row = tm * 128 + wr * 64 + m * 16 + (lane >> 4) * 4 + r;
                    int col = wc * 32 + n * 16 + r16;   // 0..63 within head
                    size_t off = (size_t)tn * (SEQ * HD) + (size_t)row * HD + col;
                    Qp[off] = (_Float16)(accQ[m][n][r] * QSCALE);
                    Kp[off] = (_Float16)accK[m][n][r];
                }
            }
        }
    } else {
        int tm = rem & 7, tn = rem >> 3;             // 8 m x 32 n
        floatx4 acc[4][2] = {};
        gemm_core64(Wt + (size_t)2 * DIM * DIM + (size_t)tm * 128 * DIM,
                    Hf + (size_t)tn * 64 * DIM, lds, acc);
        #pragma unroll
        for (int m = 0; m < 4; m++) {
            #pragma unroll
            for (int n = 0; n < 2; n++) {
                #pragma unroll
                for (int r = 0; r < 4; r++) {
                    int row = tm * 128 + wr * 64 + m * 16 + (lane >> 4) * 4 + r;
                    int col = tn * 64 + wc * 32 + n * 16 + r16;
                    Vt[(size_t)row * SEQ + col] = (_Float16)acc[m][n][r];
                }
            }
        }
    }
}

// ---------------- 5. output projection + bias: 128x64 tiles, 256 WGs = 1/CU -------
__global__ __launch_bounds__(256) void gemm_o(
        const _Float16* __restrict__ AO, const _Float16* __restrict__ WoT,
        const float* __restrict__ bias, float* __restrict__ out) {
    __shared__ char lds[49152];
    floatx4 acc[4][2] = {};

    int lin = blockIdx.x + 16 * blockIdx.y;      // 0..255
    int swz = (lin & 7) * 32 + (lin >> 3);       // 256 % 8 == 0 -> bijective
    int tm = swz & 15, tn = swz >> 4;            // 16 x 16

    gemm_core64(AO + (size_t)tm * 128 * DIM, WoT + (size_t)tn * 64 * DIM, lds, acc);

    int lane = threadIdx.x & 63, wid = threadIdx.x >> 6;
    int wr = wid >> 1, wc = wid & 1;
    #pragma unroll
    for (int m = 0; m < 4; m++) {
        #pragma unroll
        for (int n = 0; n < 2; n++) {
            #pragma unroll
            for (int r = 0; r < 4; r++) {
                int row = tm * 128 + wr * 64 + m * 16 + (lane >> 4) * 4 + r;
                int col = tn * 64 + wc * 32 + n * 16 + (lane & 15);
                out[(size_t)row * DIM + col] = acc[m][n][r] + bias[col];
            }
        }
    }
}

// ---------------- 4. MFMA windowed attention (XCD-swizzled blocks) ----------------
// 1 wave per (head, f, h) row; 16 queries. Keys: 3 f-chunks x 6 h-rows x 16 w = 288.
// P_lds is WAVE-PRIVATE -> no __syncthreads needed; per-wave lgkmcnt(0) fence only.
// s_setprio(1) around MFMA clusters (T5; m191 regime: independent waves).
__global__ __launch_bounds__(256) void attn_mfma(
        const _Float16* __restrict__ Q,    // [16][2048][64] (scaled)
        const _Float16* __restrict__ K,    // [16][2048][64]
        const _Float16* __restrict__ Vt,   // [16][64][2048]
        _Float16* __restrict__ AO) {       // [2048][1024]
    __shared__ char P_lds[4][16 * 640];    // per-wave P[16 q][288 key] f16, XOR-swizzled

    int wid  = threadIdx.x >> 6;
    int lane = threadIdx.x & 63;
    int g    = lane >> 4;      // 0..3
    int ql   = lane & 15;

    int blk  = blockIdx.x;                 // 0..511
    int sblk = (blk & 7) * 64 + (blk >> 3);  // XCD-chunked, bijective (512 % 8 == 0)
    int bid  = sblk * 4 + wid;
    int rid  = bid & 127;      // (f,h)
    int head = bid >> 7;
    int f    = rid >> 4;
    int hq   = rid & 15;
    int s0   = rid << 4;

    const _Float16* Qh = Q  + (size_t)head * (SEQ * HD);
    const _Float16* Kh = K  + (size_t)head * (SEQ * HD);
    const _Float16* Vh = Vt + (size_t)head * (HD * SEQ);

    int f_start = min(max(f - 1, 0), 5);
    int h_start = min(max(hq - 2, 0), 10);

    // per-lane w-mask: key w' = g*4+r, query w = ql
    bool wm[4];
    #pragma unroll
    for (int r = 0; r < 4; r++) {
        int wp = g * 4 + r;
        wm[r] = (wp - ql <= 2) && (ql - wp <= 2);
    }

    // Q B-frags (2 k-steps over d=64)
    half8 qf[2];
    #pragma unroll
    for (int ks = 0; ks < 2; ks++)
        qf[ks] = *reinterpret_cast<const half8*>(Qh + (size_t)(s0 + ql) * HD + ks * 32 + g * 8);

    float lsum = 0.f;
    int swz = (ql & 7) << 4;

    #pragma unroll
    for (int fi = 0; fi < 3; fi++) {
        int fp = f_start + fi;
        bool fok = (fp - f <= 1) && (f - fp <= 1);
        int sbase = fp * 256 + h_start * 16;
        const _Float16* Kc = Kh + (size_t)sbase * HD;

        floatx4 sacc[6];
        #pragma unroll
        for (int j = 0; j < 6; j++) sacc[j] = (floatx4){0.f, 0.f, 0.f, 0.f};

        __builtin_amdgcn_s_setprio(1);
        #pragma unroll
        for (int j = 0; j < 6; j++) {
            #pragma unroll
            for (int ks = 0; ks < 2; ks++) {
                half8 kf = *reinterpret_cast<const half8*>(Kc + (size_t)(j * 16 + ql) * HD + ks * 32 + g * 8);
                sacc[j] = __builtin_amdgcn_mfma_f32_16x16x32_f16(kf, qf[ks], sacc[j], 0, 0, 0);
            }
        }
        __builtin_amdgcn_s_setprio(0);

        #pragma unroll
        for (int j = 0; j < 6; j++) {
            int hp = h_start + j;
            bool ok = fok && (hp - hq <= 2) && (hq - hp <= 2);
            half4 pv;
            #pragma unroll
            for (int r = 0; r < 4; r++) {
                float sv = (ok && wm[r]) ? sacc[j][r] : -10000.f;
                float p  = __builtin_amdgcn_exp2f(sv);
                lsum += p;
                pv[r] = (_Float16)p;
            }
            int byte = (ql * 640 + (fi * 96 + j * 16 + g * 4) * 2) ^ swz;
            *reinterpret_cast<half4*>(&P_lds[wid][byte]) = pv;
        }
    }

    // row sums (q = ql lives in 4 lane-groups)
    lsum += __shfl_xor(lsum, 16);
    lsum += __shfl_xor(lsum, 32);
    float inv = __builtin_amdgcn_rcpf(lsum);

    LGKM0();   // wave-private P_lds: own ds_writes retired; no cross-wave barrier needed

    floatx4 oacc[4];
    #pragma unroll
    for (int dt = 0; dt < 4; dt++) oacc[dt] = (floatx4){0.f, 0.f, 0.f, 0.f};

    #pragma unroll
    for (int fi = 0; fi < 3; fi++) {
        int sbase = (f_start + fi) * 256 + h_start * 16;
        __builtin_amdgcn_s_setprio(1);
        #pragma unroll
        for (int kw = 0; kw < 3; kw++) {
            int kcol = fi * 96 + kw * 32;
            int byte = (ql * 640 + (kcol + g * 8) * 2) ^ swz;
            half8 pa = *reinterpret_cast<half8*>(&P_lds[wid][byte]);
            #pragma unroll
            for (int dt = 0; dt < 4; dt++) {
                half8 vf = *reinterpret_cast<const half8*>(
                    Vh + (size_t)(dt * 16 + ql) * SEQ + sbase + kw * 32 + g * 8);
                oacc[dt] = __builtin_amdgcn_mfma_f32_16x16x32_f16(pa, vf, oacc[dt], 0, 0, 0);
            }
        }
        __builtin_amdgcn_s_setprio(0);
    }

    // epilogue: C row = q = g*4+rr, col = d = dt*16+ql; scale by 1/sum
    #pragma unroll
    for (int rr = 0; rr < 4; rr++) {
        float invr = __shfl(inv, g * 4 + rr);
        #pragma unroll
        for (int dt = 0; dt < 4; dt++) {
            AO[(size_t)(s0 + g * 4 + rr) * DIM + head * HD + dt * 16 + ql] =
                (_Float16)(oacc[dt][rr] * invr);
        }
    }
}

// ---------------- launch ----------------
extern "C" void kernel_launch(void* const* d_in, const int* in_sizes, int n_in,
                              void* d_out, int out_size, void* d_ws, size_t ws_size,
                              hipStream_t stream) {
    const float* H  = (const float*)d_in[0];
    const float* Wq = (const float*)d_in[1];
    const float* Wk = (const float*)d_in[2];
    const float* Wv = (const float*)d_in[3];
    const float* Wo = (const float*)d_in[4];
    const float* bo = (const float*)d_in[5];

    char* ws = (char*)d_ws;
    // layout: Hf16 [0,4M) | Wt x4 [4M,12M) | Q [12M,16M) | K [16M,20M) | Vt [20M,24M) | AO [24M,28M)
    _Float16* Hf = (_Float16*)(ws);
    _Float16* Wt = (_Float16*)(ws + (4u  << 20));
    _Float16* Qp = (_Float16*)(ws + (12u << 20));
    _Float16* Kp = (_Float16*)(ws + (16u << 20));
    _Float16* Vt = (_Float16*)(ws + (20u << 20));
    _Float16* AO = (_Float16*)(ws + (24u << 20));

    // 1+2. H -> f16 and weights -> transposed f16 (vectorized)
    prep<<<dim3(16, 16, 5), 256, 0, stream>>>(H, Hf, Wq, Wk, Wv, Wo, Wt);

    // 3. QKV projections: z=0 fused Q+K (shared A-tile), z=1 V^T; 512 WGs = 2/CU
    gemm_qkv<<<dim3(256, 1, 2), 256, 0, stream>>>(Hf, Wt, Qp, Kp, Vt);

    // 4. windowed MFMA attention: 2048 one-wave rows, 4 per block
    attn_mfma<<<dim3(NHEAD * 128 / 4), 256, 0, stream>>>(Qp, Kp, Vt, AO);

    // 5. output projection + bias: 256 WGs = 1 block/CU
    gemm_o<<<dim3(16, 16), 256, 0, stream>>>(AO, Wt + (size_t)3 * DIM * DIM, bo, (float*)d_out);
}

// Round 14
// 58.776 us; speedup vs baseline: 1.0409x; 1.0409x over previous
//
#include <hip/hip_runtime.h>
#include <hip/hip_bf16.h>
#include <hip/hip_fp16.h>

// ---------------- constants (problem is fixed-shape) ----------------
#define SEQ   2048
#define DIM   1024
#define NHEAD 16
#define HD    64
// grid (8,16,16), window (3,5,5) -> half windows 1,2,2
#define QSCALE 0.18033688011112042f   // (1/sqrt(64)) * log2(e), folded into Q

typedef _Float16 half8 __attribute__((ext_vector_type(8)));
typedef _Float16 half4 __attribute__((ext_vector_type(4)));
typedef float    floatx4 __attribute__((ext_vector_type(4)));

// async global->LDS, 16B per lane; LDS dest is wave-uniform base + lane*16
__device__ __forceinline__ void gload16(const void* g, void* l) {
    __builtin_amdgcn_global_load_lds(
        (const __attribute__((address_space(1))) unsigned int*)g,
        (__attribute__((address_space(3))) unsigned int*)l, 16, 0, 0);
}

#define VMCNT(n) asm volatile("s_waitcnt vmcnt(" #n ")" ::: "memory")
#define LGKM0()  asm volatile("s_waitcnt lgkmcnt(0)" ::: "memory")
#define BAR()    __builtin_amdgcn_s_barrier()

// ---------------- 1+2 merged prep (vectorized) ----------------
// z<4: 64x64 transpose-cvt tiles through padded LDS (float4 loads, half8 stores)
// z=4: H f32->f16, float4 x2 -> half8, 32 elems/thread
__global__ __launch_bounds__(256) void prep(
        const float* __restrict__ H, _Float16* __restrict__ Hf,
        const float* __restrict__ W0, const float* __restrict__ W1,
        const float* __restrict__ W2, const float* __restrict__ W3,
        _Float16* __restrict__ T) {
    __shared__ float tile[64][65];    // +1 pad: both phases <=2-way bank aliasing
    int z = blockIdx.z;
    int t = threadIdx.x;
    if (z < 4) {
        const float* W = (z == 0) ? W0 : (z == 1) ? W1 : (z == 2) ? W2 : W3;
        _Float16* Tz = T + (size_t)z * (DIM * DIM);
        int bx = blockIdx.x * 64;     // n base
        int by = blockIdx.y * 64;     // k base
        #pragma unroll
        for (int i = 0; i < 4; i++) {
            int id = t + i * 256;
            int r = id >> 4;                  // k_local 0..63
            int c = (id & 15) * 4;            // n_local 0..60
            float4 v = *reinterpret_cast<const float4*>(W + (size_t)(by + r) * DIM + bx + c);
            tile[r][c] = v.x; tile[r][c + 1] = v.y; tile[r][c + 2] = v.z; tile[r][c + 3] = v.w;
        }
        __syncthreads();
        #pragma unroll
        for (int i = 0; i < 2; i++) {
            int id = t + i * 256;
            int nr = id >> 3;                 // n_local 0..63
            int c8 = id & 7;                  // k chunk
            half8 o;
            #pragma unroll
            for (int j = 0; j < 8; j++) o[j] = (_Float16)tile[c8 * 8 + j][nr];
            *reinterpret_cast<half8*>(Tz + (size_t)(bx + nr) * DIM + by + c8 * 8) = o;
        }
    } else {
        int wg = blockIdx.y * 16 + blockIdx.x;   // 0..255
        #pragma unroll
        for (int i = 0; i < 4; i++) {
            int base = ((wg * 4 + i) * 256 + t) * 8;
            float4 v0 = *reinterpret_cast<const float4*>(H + base);
            float4 v1 = *reinterpret_cast<const float4*>(H + base + 4);
            half8 o = { (_Float16)v0.x, (_Float16)v0.y, (_Float16)v0.z, (_Float16)v0.w,
                        (_Float16)v1.x, (_Float16)v1.y, (_Float16)v1.z, (_Float16)v1.w };
            *reinterpret_cast<half8*>(Hf + base) = o;
        }
    }
}

// ---------------- GEMM core: 128x64 tile, BK=64, 2-deep counted-vmcnt pipeline ----
// (round-11 proven best) 4 waves (2x2), wave tile 64x32 = 4x2 frags.
// LDS/buffer: A 16KB + B 8KB = 24KB; 2 buffers = 48KB. vmcnt(6); never 0 in loop.
__device__ __forceinline__ void gemm_core64(const _Float16* __restrict__ Ap,
                                            const _Float16* __restrict__ Bp,
                                            char* lds, floatx4 (&acc)[4][2]) {
    const int tid  = threadIdx.x;
    const int lane = tid & 63;
    const int wid  = tid >> 6;
    const int wr = wid >> 1, wc = wid & 1;
    const int r16 = lane & 15;
    const int kk  = (lane >> 4) * 8;

    const int srow = tid >> 2, scol = (tid & 3) * 8;
    const _Float16* As0 = Ap + (size_t)srow * DIM + scol;   // rows 0..63 (+64 via i&1)
    const _Float16* Bs0 = Bp + (size_t)srow * DIM + scol;   // rows 0..63

    auto stage = [&](int buf, int t) {
        char* Ad = lds + buf * 24576;
        char* Bd = Ad + 16384;
        int k0 = t * 64;
        #pragma unroll
        for (int i = 0; i < 4; i++) {        // A: two row-halves x two ks-halves
            int off = (i & 1) * 64 * DIM + (i >> 1) * 32 + k0;
            gload16(As0 + off, Ad + i * 4096 + wid * 1024);
        }
        #pragma unroll
        for (int j = 0; j < 2; j++)          // B: 64 rows, ks-half j
            gload16(Bs0 + j * 32 + k0, Bd + j * 4096 + wid * 1024);
    };

    auto compute = [&](int buf) {
        char* Ad = lds + buf * 24576;
        char* Bd = Ad + 16384;
        #pragma unroll
        for (int ks = 0; ks < 2; ks++) {
            half8 a[4], b[2];
            #pragma unroll
            for (int m = 0; m < 4; m++)
                a[m] = *reinterpret_cast<half8*>(Ad + ks * 8192 + (wr * 64 + m * 16 + r16) * 64 + kk * 2);
            #pragma unroll
            for (int n = 0; n < 2; n++)
                b[n] = *reinterpret_cast<half8*>(Bd + ks * 4096 + (wc * 32 + n * 16 + r16) * 64 + kk * 2);
            #pragma unroll
            for (int m = 0; m < 4; m++)
                #pragma unroll
                for (int n = 0; n < 2; n++)
                    acc[m][n] = __builtin_amdgcn_mfma_f32_16x16x32_f16(a[m], b[n], acc[m][n], 0, 0, 0);
        }
    };

    stage(0, 0);
    stage(1, 1);                               // 12 loads/wave outstanding
    #pragma unroll 1
    for (int t = 0; t < 14; t += 2) {
        VMCNT(6); BAR();
        compute(0);
        BAR();
        stage(0, t + 2);
        VMCNT(6); BAR();
        compute(1);
        BAR();
        stage(1, t + 3);
    }
    VMCNT(6); BAR();
    compute(0);
    BAR();
    VMCNT(0); BAR();
    compute(1);
}

// ---------------- 3. fused QKV projections: 128x64 tiles, 768 WGs = 3/CU ----------
// z=0: Q = H*Wq^T (scaled, per-head layout)  z=1: K (per-head layout)
// z=2: V^T = Wv^T * H^T  (row-major [1024][2048])
__global__ __launch_bounds__(256) void gemm_qkv(
        const _Float16* __restrict__ Hf, const _Float16* __restrict__ Wt,
        _Float16* __restrict__ Qp, _Float16* __restrict__ Kp, _Float16* __restrict__ Vt) {
    __shared__ char lds[49152];
    floatx4 acc[4][2] = {};

    // XCD-aware chunked remap of 768 workgroups (768 % 8 == 0 -> bijective)
    int lin = blockIdx.x + 256 * blockIdx.z;     // 0..767
    int swz = (lin & 7) * 96 + (lin >> 3);
    int z   = swz >> 8;            // 0..2
    int rem = swz & 255;

    int tm, tn;
    const _Float16 *Ap, *Bp;
    if (z < 2) {
        tm = rem & 15; tn = rem >> 4;                           // 16 m x 16 n
        Ap = Hf + (size_t)tm * 128 * DIM;
        Bp = Wt + (size_t)z * DIM * DIM + (size_t)tn * 64 * DIM;
    } else {
        tm = rem & 7; tn = rem >> 3;                            // 8 m x 32 n
        Ap = Wt + (size_t)2 * DIM * DIM + (size_t)tm * 128 * DIM;
        Bp = Hf + (size_t)tn * 64 * DIM;
    }
    gemm_core64(Ap, Bp, lds, acc);

    int lane = threadIdx.x & 63, wid = threadIdx.x >> 6;
    int wr = wid >> 1, wc = wid & 1;
    float qs = (z == 0) ? QSCALE : 1.0f;
    _Float16* Oz = (z == 0) ? Qp : Kp;

    #pragma unroll
    for (int m = 0; m < 4; m++) {
        #pragma unroll
        for (int n = 0; n < 2; n++) {
            #pragma unroll
            for (int r = 0; r < 4; r++) {
                int row = tm * 128 + wr * 64 + m * 16 + (lane >> 4) * 4 + r;
                int col = tn * 64 + wc * 32 + n * 16 + (lane & 15);
                float v = acc[m][n][r];
                if (z < 2) {
                    int head = col >> 6;       // == tn
                    Oz[(size_t)head * (SEQ * HD) + (size_t)row * HD + (col & 63)] = (_Float16)(v * qs);
                } else {
                    Vt[(size_t)row * SEQ + col] = (_Float16)v;
                }
            }
        }
    }
}

// ---------------- 5. output projection + bias: 128x64 tiles, 256 WGs = 1/CU -------
__global__ __launch_bounds__(256) void gemm_o(
        const _Float16* __restrict__ AO, const _Float16* __restrict__ WoT,
        const float* __restrict__ bias, float* __restrict__ out) {
    __shared__ char lds[49152];
    floatx4 acc[4][2] = {};

    int lin = blockIdx.x + 16 * blockIdx.y;      // 0..255
    int swz = (lin & 7) * 32 + (lin >> 3);       // 256 % 8 == 0 -> bijective
    int tm = swz & 15, tn = swz >> 4;            // 16 x 16

    gemm_core64(AO + (size_t)tm * 128 * DIM, WoT + (size_t)tn * 64 * DIM, lds, acc);

    int lane = threadIdx.x & 63, wid = threadIdx.x >> 6;
    int wr = wid >> 1, wc = wid & 1;
    #pragma unroll
    for (int m = 0; m < 4; m++) {
        #pragma unroll
        for (int n = 0; n < 2; n++) {
            #pragma unroll
            for (int r = 0; r < 4; r++) {
                int row = tm * 128 + wr * 64 + m * 16 + (lane >> 4) * 4 + r;
                int col = tn * 64 + wc * 32 + n * 16 + (lane & 15);
                out[(size_t)row * DIM + col] = acc[m][n][r] + bias[col];
            }
        }
    }
}

// ---------------- 4. MFMA windowed attention (XCD-swizzled, masked-work skipping) --
// 1 wave per (head, f, h) row; 16 queries. Keys: 3 f-chunks x 6 h-rows x 16 w = 288,
// but only <=75 valid. All mask terms in f and h are WAVE-UNIFORM -> skip dead
// f-chunks entirely (QK^T AND PV) and dead h-rows (K-load+MFMA+exp -> zero-P write).
__global__ __launch_bounds__(256) void attn_mfma(
        const _Float16* __restrict__ Q,    // [16][2048][64] (scaled)
        const _Float16* __restrict__ K,    // [16][2048][64]
        const _Float16* __restrict__ Vt,   // [16][64][2048]
        _Float16* __restrict__ AO) {       // [2048][1024]
    __shared__ char P_lds[4][16 * 640];    // per-wave P[16 q][288 key] f16, XOR-swizzled

    int wid  = threadIdx.x >> 6;
    int lane = threadIdx.x & 63;
    int g    = lane >> 4;      // 0..3
    int ql   = lane & 15;

    int blk  = blockIdx.x;                 // 0..511
    int sblk = (blk & 7) * 64 + (blk >> 3);  // XCD-chunked, bijective (512 % 8 == 0)
    int bid  = sblk * 4 + wid;
    int rid  = bid & 127;      // (f,h)
    int head = bid >> 7;
    int f    = rid >> 4;
    int hq   = rid & 15;
    int s0   = rid << 4;

    const _Float16* Qh = Q  + (size_t)head * (SEQ * HD);
    const _Float16* Kh = K  + (size_t)head * (SEQ * HD);
    const _Float16* Vh = Vt + (size_t)head * (HD * SEQ);

    int f_start = min(max(f - 1, 0), 5);
    int h_start = min(max(hq - 2, 0), 10);

    // per-lane w-mask: key w' = g*4+r, query w = ql
    bool wm[4];
    #pragma unroll
    for (int r = 0; r < 4; r++) {
        int wp = g * 4 + r;
        wm[r] = (wp - ql <= 2) && (ql - wp <= 2);
    }

    // Q B-frags (2 k-steps over d=64)
    half8 qf[2];
    #pragma unroll
    for (int ks = 0; ks < 2; ks++)
        qf[ks] = *reinterpret_cast<const half8*>(Qh + (size_t)(s0 + ql) * HD + ks * 32 + g * 8);

    float lsum = 0.f;
    int swz = (ql & 7) << 4;

    // wave-uniform chunk/row validity
    bool fokv[3];
    #pragma unroll
    for (int fi = 0; fi < 3; fi++) {
        int fp = f_start + fi;
        fokv[fi] = (fp - f <= 1) && (f - fp <= 1);
    }

    #pragma unroll
    for (int fi = 0; fi < 3; fi++) {
        int sbase = (f_start + fi) * 256 + h_start * 16;
        const _Float16* Kc = Kh + (size_t)sbase * HD;

        if (fokv[fi]) {
            #pragma unroll
            for (int j = 0; j < 6; j++) {
                int hp = h_start + j;
                bool hok = (hp - hq <= 2) && (hq - hp <= 2);   // wave-uniform
                int byte = (ql * 640 + (fi * 96 + j * 16 + g * 4) * 2) ^ swz;
                if (hok) {
                    floatx4 sacc = (floatx4){0.f, 0.f, 0.f, 0.f};
                    __builtin_amdgcn_s_setprio(1);
                    #pragma unroll
                    for (int ks = 0; ks < 2; ks++) {
                        half8 kf = *reinterpret_cast<const half8*>(Kc + (size_t)(j * 16 + ql) * HD + ks * 32 + g * 8);
                        sacc = __builtin_amdgcn_mfma_f32_16x16x32_f16(kf, qf[ks], sacc, 0, 0, 0);
                    }
                    __builtin_amdgcn_s_setprio(0);
                    half4 pv;
                    #pragma unroll
                    for (int r = 0; r < 4; r++) {
                        float p = wm[r] ? __builtin_amdgcn_exp2f(sacc[r]) : 0.f;
                        lsum += p;
                        pv[r] = (_Float16)p;
                    }
                    *reinterpret_cast<half4*>(&P_lds[wid][byte]) = pv;
                } else {
                    *reinterpret_cast<half4*>(&P_lds[wid][byte]) = (half4){0, 0, 0, 0};
                }
            }
        }
        // dead f-chunk: PV skips it entirely; no P needed
    }

    // row sums (q = ql lives in 4 lane-groups)
    lsum += __shfl_xor(lsum, 16);
    lsum += __shfl_xor(lsum, 32);
    float inv = __builtin_amdgcn_rcpf(lsum);

    LGKM0();   // wave-private P_lds: own ds_writes retired; no cross-wave barrier needed

    floatx4 oacc[4];
    #pragma unroll
    for (int dt = 0; dt < 4; dt++) oacc[dt] = (floatx4){0.f, 0.f, 0.f, 0.f};

    #pragma unroll
    for (int fi = 0; fi < 3; fi++) {
        if (!fokv[fi]) continue;               // wave-uniform skip: 12 MFMA + 12 loads saved
        int sbase = (f_start + fi) * 256 + h_start * 16;
        __builtin_amdgcn_s_setprio(1);
        #pragma unroll
        for (int kw = 0; kw < 3; kw++) {
            int kcol = fi * 96 + kw * 32;
            int byte = (ql * 640 + (kcol + g * 8) * 2) ^ swz;
            half8 pa = *reinterpret_cast<half8*>(&P_lds[wid][byte]);
            #pragma unroll
            for (int dt = 0; dt < 4; dt++) {
                half8 vf = *reinterpret_cast<const half8*>(
                    Vh + (size_t)(dt * 16 + ql) * SEQ + sbase + kw * 32 + g * 8);
                oacc[dt] = __builtin_amdgcn_mfma_f32_16x16x32_f16(pa, vf, oacc[dt], 0, 0, 0);
            }
        }
        __builtin_amdgcn_s_setprio(0);
    }

    // epilogue: C row = q = g*4+rr, col = d = dt*16+ql; scale by 1/sum
    #pragma unroll
    for (int rr = 0; rr < 4; rr++) {
        float invr = __shfl(inv, g * 4 + rr);
        #pragma unroll
        for (int dt = 0; dt < 4; dt++) {
            AO[(size_t)(s0 + g * 4 + rr) * DIM + head * HD + dt * 16 + ql] =
                (_Float16)(oacc[dt][rr] * invr);
        }
    }
}

// ---------------- launch ----------------
extern "C" void kernel_launch(void* const* d_in, const int* in_sizes, int n_in,
                              void* d_out, int out_size, void* d_ws, size_t ws_size,
                              hipStream_t stream) {
    const float* H  = (const float*)d_in[0];
    const float* Wq = (const float*)d_in[1];
    const float* Wk = (const float*)d_in[2];
    const float* Wv = (const float*)d_in[3];
    const float* Wo = (const float*)d_in[4];
    const float* bo = (const float*)d_in[5];

    char* ws = (char*)d_ws;
    // layout: Hf16 [0,4M) | Wt x4 [4M,12M) | Q [12M,16M) | K [16M,20M) | Vt [20M,24M) | AO [24M,28M)
    _Float16* Hf = (_Float16*)(ws);
    _Float16* Wt = (_Float16*)(ws + (4u  << 20));
    _Float16* Qp = (_Float16*)(ws + (12u << 20));
    _Float16* Kp = (_Float16*)(ws + (16u << 20));
    _Float16* Vt = (_Float16*)(ws + (20u << 20));
    _Float16* AO = (_Float16*)(ws + (24u << 20));

    // 1+2. H -> f16 and weights -> transposed f16 (vectorized)
    prep<<<dim3(16, 16, 5), 256, 0, stream>>>(H, Hf, Wq, Wk, Wv, Wo, Wt);

    // 3. fused Q, K, V^T projections: 128x64 tiles, 768 WGs = exactly 3/CU
    gemm_qkv<<<dim3(256, 1, 3), 256, 0, stream>>>(Hf, Wt, Qp, Kp, Vt);

    // 4. windowed MFMA attention: 2048 one-wave rows, 4 per block
    attn_mfma<<<dim3(NHEAD * 128 / 4), 256, 0, stream>>>(Qp, Kp, Vt, AO);

    // 5. output projection + bias: 256 WGs = 1 block/CU
    gemm_o<<<dim3(16, 16), 256, 0, stream>>>(AO, Wt + (size_t)3 * DIM * DIM, bo, (float*)d_out);
}